// Round 9
// baseline (232.209 us; speedup 1.0000x reference)
//
#include <hip/hip_runtime.h>
#include <hip/hip_bf16.h>
#include <stdint.h>

// ---------------- types / helpers ----------------
typedef __attribute__((ext_vector_type(8))) short bf16x8;
typedef __attribute__((ext_vector_type(4))) float f32x4;
typedef __attribute__((ext_vector_type(4))) int   i32x4;

#define DEV static __device__ __forceinline__

DEV float bf2f(short s) {
    unsigned u = ((unsigned)(unsigned short)s) << 16;
    return __builtin_bit_cast(float, u);
}
DEV short f2bf(float f) {  // RNE (software; prep/branch paths)
    unsigned u = __builtin_bit_cast(unsigned, f);
    unsigned r = u + 0x7fffu + ((u >> 16) & 1u);
    return (short)(r >> 16);
}
DEV unsigned cvt_pk_bf16(float lo, float hi) {  // single HW instr
    unsigned r;
    asm("v_cvt_pk_bf16_f32 %0, %1, %2" : "=v"(r) : "v"(lo), "v"(hi));
    return r;
}

// problem constants
#define PTOT 32768
#define NEXP2 (-2.885390081777927f)   // -2*log2(e)

// ws byte offsets (same footprint as before; arrays now fragment-major)
#define WS_WC1F 0          // wc1f: 16384 shorts
#define WS_WC2F 32768      // wc2f: 16384 shorts
#define WS_WD1F 65536      // wd1f: 147456 shorts
#define WS_WF   360448     // Wf:   589824 shorts
#define WS_EKT  1540096
#define WS_EN   2719744
#define WS_XT   19496960   // xT8: 8*66*32*66*8 bf16 = 17842176 B ; total ~37.3 MB

// ---------------- prep: fragment-major weight reorder + bf16 cast ----------------
// A wave's MFMA B-fragment = contiguous 1KB at (fragment_index*64 + lane)*8 shorts.
// Wf  [kt=72][ot=16][lane][8] : kt = k3x3*8+nchunk ; o = ot*16+(lane&15);
//                               n = (kt&7)*32+(lane>>4)*8+i ; val = 2*W[o][n][kt>>3]
// wd1f[kc=72][wv=4 ][lane][8] : m = wv*16+(lane&15); n = (kc&7)*32+(lane>>4)*8+i; w_d1[m][n][kc>>3]
// wc1f[s=8  ][wv=4 ][lane][8] : m = wv*16+(lane&15); n = s*32+(lane>>4)*8+i;      w_c1[m][n]
// wc2f[s=2  ][ot=16][lane][8] : o = ot*16+(lane&15); kk = s*32+(lane>>4)*8+i;     w_c2[o][kk]
__global__ __launch_bounds__(256) void k_prep(const float* __restrict__ W, const float* __restrict__ w_d1,
                                              const float* __restrict__ w_c1, const float* __restrict__ w_c2,
                                              short* __restrict__ Wf, short* __restrict__ wd1f,
                                              short* __restrict__ wc1f, short* __restrict__ wc2f) {
    int t = blockIdx.x * 256 + threadIdx.x;
    if (t < 589824) {
        int i = t & 7, lane = (t >> 3) & 63, ot = (t >> 9) & 15, kt = t >> 13;   // kt < 72
        int o = ot * 16 + (lane & 15);
        int n = (kt & 7) * 32 + (lane >> 4) * 8 + i;
        Wf[t] = f2bf(2.0f * W[o * 2304 + n * 9 + (kt >> 3)]);
    } else if (t < 589824 + 147456) {
        int t2 = t - 589824;
        int i = t2 & 7, lane = (t2 >> 3) & 63, wv = (t2 >> 9) & 3, kc = t2 >> 11; // kc < 72
        int m = wv * 16 + (lane & 15);
        int n = (kc & 7) * 32 + (lane >> 4) * 8 + i;
        wd1f[t2] = f2bf(w_d1[m * 2304 + n * 9 + (kc >> 3)]);
    } else if (t < 589824 + 147456 + 16384) {
        int t3 = t - (589824 + 147456);
        int i = t3 & 7, lane = (t3 >> 3) & 63, wv = (t3 >> 9) & 3, s = t3 >> 11;  // s < 8
        int m = wv * 16 + (lane & 15);
        int n = s * 32 + (lane >> 4) * 8 + i;
        wc1f[t3] = f2bf(w_c1[m * 256 + n]);
    } else if (t < 589824 + 147456 + 32768) {
        int t4 = t - (589824 + 147456 + 16384);
        int i = t4 & 7, lane = (t4 >> 3) & 63, ot = (t4 >> 9) & 15, s = t4 >> 13; // s < 2
        int o = ot * 16 + (lane & 15);
        int kk = s * 32 + (lane >> 4) * 8 + i;
        wc2f[t4] = f2bf(w_c2[o * 64 + kk]);
    }
}

// ---------------- prep: padded x in n-pack layout ----------------
// xT8[b][hp][np][wp][8] bf16 : hp,wp in [0,66) (borders zero), np = n>>3 (32 packs).
__global__ __launch_bounds__(256) void k_prep_xt(const float* __restrict__ x, short* __restrict__ xT8) {
    __shared__ short t[64 * 74];
    const int rw = blockIdx.x;     // 512: b = rw>>6, hr = rw&63
    const int b = rw >> 6, hr = rw & 63;
    const int tid = threadIdx.x;
    const int hp = hr + 1;
    #define XI(HP, NP, WP) ((((size_t)(b) * 66 + (HP)) * 32 + (NP)) * 66 + (WP)) * 8
    if (tid < 64) {   // zero wp borders for this row
        int np = tid & 31, wp = (tid & 32) ? 65 : 0;
        *(i32x4*)(xT8 + XI(hp, np, wp)) = i32x4{0, 0, 0, 0};
    }
    if (hr == 0) {    // zero full hp=0,65 planes for this b
        for (int i = tid; i < 2 * 32 * 66; i += 256) {
            int pl = (i >= 32 * 66) ? 65 : 0;
            int rem = (i >= 32 * 66) ? i - 32 * 66 : i;
            int np = rem / 66, wp = rem - np * 66;
            *(i32x4*)(xT8 + XI(pl, np, wp)) = i32x4{0, 0, 0, 0};
        }
    }
    const int dn = tid >> 6, w = tid & 63;
    for (int p = 0; p < 4; ++p) {
        __syncthreads();
        #pragma unroll
        for (int jj = 0; jj < 16; ++jj) {
            int n = p * 64 + dn * 16 + jj;
            t[w * 74 + dn * 16 + jj] = f2bf(x[(((size_t)(b * 256 + n) * 64) + hr) * 64 + w]);
        }
        __syncthreads();
        #pragma unroll
        for (int q = 0; q < 2; ++q) {
            int nl = q * 4 + dn;
            *(bf16x8*)(xT8 + XI(hp, p * 8 + nl, w + 1)) = *(const bf16x8*)(t + w * 74 + nl * 8);
        }
    }
    #undef XI
}

// ---------------- shared x staging (k_branch) ----------------
// xs layout: [3][66][XSTR] bf16, XSTR=268 (conflict-free b128 at px-stride reads).
#define XSTR 268
DEV void stage_xs3(short* xs, const float* __restrict__ x, int b, int h0) {
    const int tid = threadIdx.x;  // 512 threads
    for (int i = tid; i < 3 * 256; i += 512) {  // zero pads c=0,65
        int r = i >> 8, rem = i & 255;
        int cc = (rem >> 7) ? 65 : 0, ch2 = (rem & 127) * 2;
        *(int*)(xs + (r * 66 + cc) * XSTR + ch2) = 0;
    }
    const int w4 = (tid & 15) * 4;
    const int chp = tid >> 4;  // 0..31
    for (int r = 0; r < 3; ++r) {
        int hr = h0 + r;
        bool inb = (hr >= 0) && (hr < 64);
        for (int pass = 0; pass < 4; ++pass) {
            int c0 = (pass * 32 + chp) * 2;
            f32x4 v0 = {0.f, 0.f, 0.f, 0.f}, v1 = {0.f, 0.f, 0.f, 0.f};
            if (inb) {
                v0 = *(const f32x4*)(x + (((size_t)(b * 256 + c0)     * 64 + hr) << 6) + w4);
                v1 = *(const f32x4*)(x + (((size_t)(b * 256 + c0 + 1) * 64 + hr) << 6) + w4);
            }
            #pragma unroll
            for (int j = 0; j < 4; ++j)
                *(int*)(xs + (r * 66 + w4 + j + 1) * XSTR + c0) =
                    (unsigned)(unsigned short)f2bf(v0[j]) | ((unsigned)(unsigned short)f2bf(v1[j]) << 16);
        }
    }
}

// ---------------- branch kernel: en (= e^{-2c}) and ekT (= e^{-2d}) ----------------
// LDS: xs [3][66][268] 106128 | yc [64][72] bf16 9216 | ydl [64][67] f32 17152 = 132496
// ent [64][264] bf16 (33792) reuses xs region after conv.
#define BR_YC    106128
#define BR_YD    (BR_YC + 9216)
#define BR_TOTAL (BR_YD + 17152)   // 132496

__global__ __launch_bounds__(512, 1) void k_branch(const float* __restrict__ x,
        const float* __restrict__ b_c1, const float* __restrict__ b_c2,
        const float* __restrict__ b_d1, const float* __restrict__ w_d2, const float* __restrict__ b_d2,
        const short* __restrict__ wc1f, const short* __restrict__ wc2f, const short* __restrict__ wd1f,
        short* __restrict__ en, float* __restrict__ ekT) {
    extern __shared__ char smem[];
    short* xs  = (short*)smem;
    short* yc  = (short*)(smem + BR_YC);
    float* ydl = (float*)(smem + BR_YD);
    short* ent = (short*)smem;   // valid after xs dead

    const int rw = blockIdx.x;        // 512 blocks, 64 px (one row) each
    const int b = rw >> 6, h = rw & 63;
    const int p0 = rw << 6;
    const int tid = threadIdx.x;
    const int lane = tid & 63, wave = tid >> 6;
    const int l16 = lane & 15, lg = lane >> 4;
    const int wn = wave & 3, wm = wave >> 2;   // 2 (M) x 4 (N)
    const int cm = wn * 16 + l16;

    stage_xs3(xs, x, b, h - 1);
    __syncthreads();

    // ---- GEMM1: yc[64px][64cm] = relu(x . w_c1^T + b_c1); B coalesced frags (s stride 2048)
    {
        f32x4 acc[2] = {};
        const short* wp = wc1f + wn * 512 + lane * 8;
        bf16x8 bp = *(const bf16x8*)(wp);
        #pragma unroll
        for (int s = 0; s < 8; ++s) {
            bf16x8 bc = bp;
            if (s < 7) bp = *(const bf16x8*)(wp + (s + 1) * 2048);
            #pragma unroll
            for (int mt = 0; mt < 2; ++mt) {
                int px = wm * 32 + mt * 16 + l16;
                bf16x8 afr = *(const bf16x8*)(xs + (66 + px + 1) * XSTR + s * 32 + lg * 8);
                acc[mt] = __builtin_amdgcn_mfma_f32_16x16x32_bf16(afr, bc, acc[mt], 0, 0, 0);
            }
        }
        float bias = b_c1[cm];
        #pragma unroll
        for (int mt = 0; mt < 2; ++mt)
            #pragma unroll
            for (int r = 0; r < 4; ++r) {
                int px = wm * 32 + mt * 16 + lg * 4 + r;
                float v = acc[mt][r] + bias;
                yc[px * 72 + cm] = f2bf(v > 0.f ? v : 0.f);
            }
    }

    // ---- conv GEMM: yd[64px][64cm] = relu(conv3x3 + b_d1); B coalesced frags, 3-deep prefetch
    {
        f32x4 acc[2] = {};
        const short* wp = wd1f + wn * 512 + lane * 8;   // kc stride 2048
        bf16x8 bp0 = *(const bf16x8*)(wp);
        bf16x8 bp1 = *(const bf16x8*)(wp + 2048);
        bf16x8 bp2 = *(const bf16x8*)(wp + 4096);
        for (int kc = 0; kc < 72; ++kc) {
            bf16x8 bc = bp0;
            bp0 = bp1; bp1 = bp2;
            int c3 = (kc + 3 < 72) ? kc + 3 : 71;
            bp2 = *(const bf16x8*)(wp + c3 * 2048);
            int k = kc >> 3, n0 = (kc & 7) << 5;
            int kh = k / 3, kw = k - kh * 3;
            #pragma unroll
            for (int mt = 0; mt < 2; ++mt) {
                int px = wm * 32 + mt * 16 + l16;
                bf16x8 afr = *(const bf16x8*)(xs + (kh * 66 + px + kw) * XSTR + n0 + lg * 8);
                acc[mt] = __builtin_amdgcn_mfma_f32_16x16x32_bf16(afr, bc, acc[mt], 0, 0, 0);
            }
        }
        float bias = b_d1[cm];
        #pragma unroll
        for (int mt = 0; mt < 2; ++mt)
            #pragma unroll
            for (int r = 0; r < 4; ++r) {
                int px = wm * 32 + mt * 16 + lg * 4 + r;
                float v = acc[mt][r] + bias;
                ydl[px * 67 + cm] = v > 0.f ? v : 0.f;
            }
    }
    __syncthreads();   // yc + ydl ready; xs dead -> ent usable

    // ---- GEMM2: c[64px][256] = yc . w_c2^T + b_c2 ; ent = exp(-2c); B coalesced frags
    {
        f32x4 acc[2][4] = {};
        #pragma unroll
        for (int s = 0; s < 2; ++s) {
            int k0 = s * 32;
            bf16x8 afr[2], bfr[4];
            #pragma unroll
            for (int mt = 0; mt < 2; ++mt)
                afr[mt] = *(const bf16x8*)(yc + (wm * 32 + mt * 16 + l16) * 72 + k0 + lg * 8);
            #pragma unroll
            for (int nt = 0; nt < 4; ++nt)
                bfr[nt] = *(const bf16x8*)(wc2f + s * 8192 + (wn * 4 + nt) * 512 + lane * 8);
            #pragma unroll
            for (int mt = 0; mt < 2; ++mt)
                #pragma unroll
                for (int nt = 0; nt < 4; ++nt)
                    acc[mt][nt] = __builtin_amdgcn_mfma_f32_16x16x32_bf16(afr[mt], bfr[nt], acc[mt][nt], 0, 0, 0);
        }
        #pragma unroll
        for (int nt = 0; nt < 4; ++nt) {
            int nc = wn * 64 + nt * 16 + l16;
            float bias = b_c2[nc];
            #pragma unroll
            for (int mt = 0; mt < 2; ++mt)
                #pragma unroll
                for (int r = 0; r < 4; ++r) {
                    int px = wm * 32 + mt * 16 + lg * 4 + r;
                    float cv = acc[mt][nt][r] + bias;
                    ent[px * 264 + nc] = f2bf(exp2f(NEXP2 * cv));
                }
        }
    }

    // ---- d[px][9] = yd . w_d2^T + b_d2 ; ekT[k][p] = exp(-2d)  (px-minor, coalesced)
    for (int t = tid; t < 576; t += 512) {
        int k = t >> 6, px = t & 63;
        float sum = b_d2[k];
        const float* yr = ydl + px * 67;
        const float* wr = w_d2 + k * 64;
        #pragma unroll 8
        for (int m = 0; m < 64; ++m) sum += yr[m] * wr[m];
        ekT[(size_t)k * PTOT + p0 + px] = exp2f(NEXP2 * sum);
    }
    __syncthreads();   // ent ready

    // ---- coalesced en store
    for (int i = tid; i < 2048; i += 512) {
        int row = i >> 5, seg = i & 31;
        *(bf16x8*)(en + (size_t)(p0 + row) * 256 + seg * 8) = *(const bf16x8*)(ent + row * 264 + seg * 8);
    }
}

// ---------------- final kernel: out = (patches*attn) . W ----------------
// 256 blocks x 128 px (2 rows), 8 waves. 9 phases; per phase:
//   load B0/B1 || issue xp loads (phase+2) || zbuild(phase+1) || GEMM(phase) || barrier
// B from Wf fragments: wave load = contiguous 1KB (was 64-way gather).
#define FN_ZSTR  268
#define FN_Z1    68608
#define FN_EKL   137216
#define FN_TOTAL 141824

__global__ __launch_bounds__(512, 1) void k_final(const short* __restrict__ xT8,
        const short* __restrict__ Wf, const short* __restrict__ en, const float* __restrict__ ekT,
        float* __restrict__ out) {
    extern __shared__ char smem[];
    short* z0  = (short*)smem;
    short* z1  = (short*)(smem + FN_Z1);
    float* ekl = (float*)(smem + FN_EKL);
    float* ot  = (float*)smem;   // epilogue reuse: [256][132] f32 = 135168 <= 141824

    const int rw = blockIdx.x;            // 256 blocks
    const int b = rw >> 5, h = (rw & 31) * 2;
    const int p0 = rw << 7;               // 128 px per block
    const int tid = threadIdx.x;
    const int lane = tid & 63, wave = tid >> 6;
    const int l16 = lane & 15, lg = lane >> 4;
    const int wn = wave & 3, wm = wave >> 2;   // GEMM: 2 (M, 64px) x 4 (N, 64o)

    for (int i = tid; i < 1152; i += 512)
        ekl[i] = ekT[(size_t)(i >> 7) * PTOT + p0 + (i & 127)];

    const int lpx = wave * 16 + l16;          // zbuild pixel
    const int r2 = lpx >> 6, ww = lpx & 63;

    // xT8 lane base: hp = h+r2+kh, np = j*4+lg, wp = ww+kw
    const short* xbase = xT8 + ((size_t)(b * 66 + h + r2) * 32 + lg) * (66 * 8) + ww * 8;

    bf16x8 e_regs[8];
    {
        const short* ep = en + (size_t)(p0 + lpx) * 256 + lg * 8;
        #pragma unroll
        for (int j = 0; j < 8; ++j) e_regs[j] = *(const bf16x8*)(ep + j * 32);
    }

    bf16x8 xpA[8], xpB[8];
    #define XLOAD(DST, KK) {                                                            \
        int kh_ = (KK) / 3, kw_ = (KK) - 3 * kh_;                                       \
        const short* xr_ = xbase + kh_ * (32 * 66 * 8) + kw_ * 8;                       \
        _Pragma("unroll")                                                               \
        for (int j = 0; j < 8; ++j) DST[j] = *(const bf16x8*)(xr_ + j * (4 * 66 * 8));  \
    }
    #define ZBUILD(ZBUF, KK, XP) {                                                      \
        float ekv = ekl[(KK) * 128 + lpx];                                              \
        short* zw_ = (ZBUF) + lpx * FN_ZSTR + lg * 8;                                   \
        _Pragma("unroll")                                                               \
        for (int j = 0; j < 8; ++j) {                                                   \
            bf16x8 x8 = XP[j]; bf16x8 e8 = e_regs[j];                                   \
            i32x4 zz;                                                                   \
            _Pragma("unroll")                                                           \
            for (int i = 0; i < 4; ++i) {                                               \
                float q0 = __builtin_fmaf(ekv, bf2f(e8[2 * i]),     1.0f);              \
                float q1 = __builtin_fmaf(ekv, bf2f(e8[2 * i + 1]), 1.0f);              \
                zz[i] = cvt_pk_bf16(bf2f(x8[2 * i])     * __builtin_amdgcn_rcpf(q0),    \
                                    bf2f(x8[2 * i + 1]) * __builtin_amdgcn_rcpf(q1));   \
            }                                                                           \
            *(i32x4*)(zw_ + j * 32) = zz;                                               \
        }                                                                               \
    }

    XLOAD(xpA, 0)
    __syncthreads();               // ekl ready (also drains xpA)
    ZBUILD(z0, 0, xpA)             // z_0
    XLOAD(xpA, 1)                  // data for z_1 (built in phase 0)
    __syncthreads();               // z0 ready

    // B fragment bases: fragment (kt = k*8+NC, ot = wn*4+nt) at Wf + kt*8192 + ot*512 + lane*8
    const short* wpB[4];
    #pragma unroll
    for (int nt = 0; nt < 4; ++nt) wpB[nt] = Wf + (wn * 4 + nt) * 512 + lane * 8;

    f32x4 acc[4][4] = {};
    const int abase = (wm * 64 + l16) * FN_ZSTR + lg * 8;

    #define GCHUNK(NC, BC, BP, DOPREF) {                                                \
        if (DOPREF) {                                                                   \
            _Pragma("unroll")                                                           \
            for (int nt = 0; nt < 4; ++nt)                                              \
                BP[nt] = *(const bf16x8*)(wpB[nt] + kbf + ((NC) + 2) * 8192);           \
        }                                                                               \
        bf16x8 afr[4];                                                                  \
        _Pragma("unroll")                                                               \
        for (int mt = 0; mt < 4; ++mt)                                                  \
            afr[mt] = *(const bf16x8*)(zR + abase + mt * 16 * FN_ZSTR + (NC) * 32);     \
        __builtin_amdgcn_s_setprio(1);                                                  \
        _Pragma("unroll")                                                               \
        for (int mt = 0; mt < 4; ++mt)                                                  \
            _Pragma("unroll")                                                           \
            for (int nt = 0; nt < 4; ++nt)                                              \
                acc[mt][nt] = __builtin_amdgcn_mfma_f32_16x16x32_bf16(afr[mt], BC[nt], acc[mt][nt], 0, 0, 0); \
        __builtin_amdgcn_s_setprio(0);                                                  \
    }
    #define PHASE(K, ZRB, ZWB, XPC, XPN) {                                              \
        const short* zR = ZRB;                                                          \
        const int kbf = (K) * 65536;                                                    \
        bf16x8 B0[4], B1[4], B2[4];                                                     \
        _Pragma("unroll")                                                               \
        for (int nt = 0; nt < 4; ++nt) {                                                \
            B0[nt] = *(const bf16x8*)(wpB[nt] + kbf);                                   \
            B1[nt] = *(const bf16x8*)(wpB[nt] + kbf + 8192);                            \
        }                                                                               \
        if ((K) + 2 <= 8) XLOAD(XPN, (K) + 2)                                           \
        if ((K) < 8) ZBUILD(ZWB, (K) + 1, XPC)                                          \
        GCHUNK(0, B0, B2, 1) GCHUNK(1, B1, B0, 1) GCHUNK(2, B2, B1, 1)                  \
        GCHUNK(3, B0, B2, 1) GCHUNK(4, B1, B0, 1) GCHUNK(5, B2, B1, 1)                  \
        GCHUNK(6, B0, B2, 0) GCHUNK(7, B1, B0, 0)                                       \
        __syncthreads();                                                                \
    }

    for (int kp = 0; kp < 4; ++kp) {
        PHASE(2 * kp,     z0, z1, xpA, xpB)
        PHASE(2 * kp + 1, z1, z0, xpB, xpA)
    }
    PHASE(8, z0, z1, xpA, xpB)

    #undef PHASE
    #undef GCHUNK
    #undef ZBUILD
    #undef XLOAD

    // epilogue: acc -> ot[o][132 px] (b128, uniform banks), then coalesced stores
    #pragma unroll
    for (int nt = 0; nt < 4; ++nt) {
        int o = wn * 64 + nt * 16 + l16;
        #pragma unroll
        for (int mt = 0; mt < 4; ++mt) {
            int px = wm * 64 + mt * 16 + lg * 4;
            *(f32x4*)(ot + o * 132 + px) = acc[mt][nt];
        }
    }
    __syncthreads();
    {
        int o = tid >> 1, half = tid & 1;
        float* dst = out + (((size_t)b * 256 + o) * 64 + h + half) * 64;
        const float* srcp = ot + o * 132 + half * 64;
        #pragma unroll
        for (int j = 0; j < 16; ++j)
            *(f32x4*)(dst + 4 * j) = *(const f32x4*)(srcp + 4 * j);
    }
}

// ---------------- launcher ----------------
extern "C" void kernel_launch(void* const* d_in, const int* in_sizes, int n_in,
                              void* d_out, int out_size, void* d_ws, size_t ws_size,
                              hipStream_t stream) {
    const float* x    = (const float*)d_in[0];
    const float* w_c1 = (const float*)d_in[1];
    const float* b_c1 = (const float*)d_in[2];
    const float* w_c2 = (const float*)d_in[3];
    const float* b_c2 = (const float*)d_in[4];
    const float* w_d1 = (const float*)d_in[5];
    const float* b_d1 = (const float*)d_in[6];
    const float* w_d2 = (const float*)d_in[7];
    const float* b_d2 = (const float*)d_in[8];
    const float* Wt   = (const float*)d_in[9];
    float* out = (float*)d_out;
    char* ws = (char*)d_ws;

    short* wc1f = (short*)(ws + WS_WC1F);
    short* wc2f = (short*)(ws + WS_WC2F);
    short* wd1f = (short*)(ws + WS_WD1F);
    short* Wf   = (short*)(ws + WS_WF);
    float* ekT  = (float*)(ws + WS_EKT);
    short* en   = (short*)(ws + WS_EN);
    short* xT8  = (short*)(ws + WS_XT);

    (void)hipFuncSetAttribute((const void*)k_branch, hipFuncAttributeMaxDynamicSharedMemorySize, BR_TOTAL);
    (void)hipFuncSetAttribute((const void*)k_final,  hipFuncAttributeMaxDynamicSharedMemorySize, FN_TOTAL);

    k_prep<<<3008, 256, 0, stream>>>(Wt, w_d1, w_c1, w_c2, Wf, wd1f, wc1f, wc2f);
    k_prep_xt<<<512, 256, 0, stream>>>(x, xT8);
    k_branch<<<512, 512, BR_TOTAL, stream>>>(x, b_c1, b_c2, b_d1, w_d2, b_d2, wc1f, wc2f, wd1f, en, ekT);
    k_final<<<256, 512, FN_TOTAL, stream>>>(xT8, Wf, en, ekT, out);
}

// Round 10
// 171.919 us; speedup vs baseline: 1.3507x; 1.3507x over previous
//
#include <hip/hip_runtime.h>
#include <hip/hip_bf16.h>
#include <stdint.h>

// ---------------- types / helpers ----------------
typedef __attribute__((ext_vector_type(8))) short bf16x8;
typedef __attribute__((ext_vector_type(4))) float f32x4;
typedef __attribute__((ext_vector_type(4))) int   i32x4;

#define DEV static __device__ __forceinline__

DEV float bf2f(short s) {
    unsigned u = ((unsigned)(unsigned short)s) << 16;
    return __builtin_bit_cast(float, u);
}
DEV short f2bf(float f) {  // RNE (software; prep paths)
    unsigned u = __builtin_bit_cast(unsigned, f);
    unsigned r = u + 0x7fffu + ((u >> 16) & 1u);
    return (short)(r >> 16);
}
DEV unsigned cvt_pk_bf16(float lo, float hi) {  // single HW instr
    unsigned r;
    asm("v_cvt_pk_bf16_f32 %0, %1, %2" : "=v"(r) : "v"(lo), "v"(hi));
    return r;
}

// problem constants
#define PTOT 32768
#define NEXP2 (-2.885390081777927f)   // -2*log2(e)

// ws byte offsets
#define WS_WC1F 0          // wc1f: 16384 shorts
#define WS_WC2F 32768      // wc2f: 16384 shorts
#define WS_WD1F 65536      // wd1f: 147456 shorts
#define WS_WF   360448     // Wf:   589824 shorts
#define WS_EKT  1540096
#define WS_EN   2719744
#define WS_XT   19496960   // xT8: 8*66*32*66*8 bf16 = 17842176 B ; total ~37.3 MB

// ---------------- prep: fragment-major weight reorder + bf16 cast ----------------
// A wave's MFMA B-fragment = contiguous 1KB at (fragment_index*64 + lane)*8 shorts.
__global__ __launch_bounds__(256) void k_prep(const float* __restrict__ W, const float* __restrict__ w_d1,
                                              const float* __restrict__ w_c1, const float* __restrict__ w_c2,
                                              short* __restrict__ Wf, short* __restrict__ wd1f,
                                              short* __restrict__ wc1f, short* __restrict__ wc2f) {
    int t = blockIdx.x * 256 + threadIdx.x;
    if (t < 589824) {
        int i = t & 7, lane = (t >> 3) & 63, ot = (t >> 9) & 15, kt = t >> 13;   // kt < 72
        int o = ot * 16 + (lane & 15);
        int n = (kt & 7) * 32 + (lane >> 4) * 8 + i;
        Wf[t] = f2bf(2.0f * W[o * 2304 + n * 9 + (kt >> 3)]);
    } else if (t < 589824 + 147456) {
        int t2 = t - 589824;
        int i = t2 & 7, lane = (t2 >> 3) & 63, wv = (t2 >> 9) & 3, kc = t2 >> 11; // kc < 72
        int m = wv * 16 + (lane & 15);
        int n = (kc & 7) * 32 + (lane >> 4) * 8 + i;
        wd1f[t2] = f2bf(w_d1[m * 2304 + n * 9 + (kc >> 3)]);
    } else if (t < 589824 + 147456 + 16384) {
        int t3 = t - (589824 + 147456);
        int i = t3 & 7, lane = (t3 >> 3) & 63, wv = (t3 >> 9) & 3, s = t3 >> 11;  // s < 8
        int m = wv * 16 + (lane & 15);
        int n = s * 32 + (lane >> 4) * 8 + i;
        wc1f[t3] = f2bf(w_c1[m * 256 + n]);
    } else if (t < 589824 + 147456 + 32768) {
        int t4 = t - (589824 + 147456 + 16384);
        int i = t4 & 7, lane = (t4 >> 3) & 63, ot = (t4 >> 9) & 15, s = t4 >> 13; // s < 2
        int o = ot * 16 + (lane & 15);
        int kk = s * 32 + (lane >> 4) * 8 + i;
        wc2f[t4] = f2bf(w_c2[o * 64 + kk]);
    }
}

// ---------------- prep: padded x in n-pack layout ----------------
// xT8[b][hp][np][wp][8] bf16 : hp,wp in [0,66) (borders zero), np = n>>3 (32 packs).
// idx = (((b*66+hp)*32+np)*66+wp)*8 ; np stride 528, hp stride 16896.
__global__ __launch_bounds__(256) void k_prep_xt(const float* __restrict__ x, short* __restrict__ xT8) {
    __shared__ short t[64 * 74];
    const int rw = blockIdx.x;     // 512: b = rw>>6, hr = rw&63
    const int b = rw >> 6, hr = rw & 63;
    const int tid = threadIdx.x;
    const int hp = hr + 1;
    #define XI(HP, NP, WP) ((((size_t)(b) * 66 + (HP)) * 32 + (NP)) * 66 + (WP)) * 8
    if (tid < 64) {   // zero wp borders for this row
        int np = tid & 31, wp = (tid & 32) ? 65 : 0;
        *(i32x4*)(xT8 + XI(hp, np, wp)) = i32x4{0, 0, 0, 0};
    }
    if (hr == 0) {    // zero full hp=0,65 planes for this b
        for (int i = tid; i < 2 * 32 * 66; i += 256) {
            int pl = (i >= 32 * 66) ? 65 : 0;
            int rem = (i >= 32 * 66) ? i - 32 * 66 : i;
            int np = rem / 66, wp = rem - np * 66;
            *(i32x4*)(xT8 + XI(pl, np, wp)) = i32x4{0, 0, 0, 0};
        }
    }
    const int dn = tid >> 6, w = tid & 63;
    for (int p = 0; p < 4; ++p) {
        __syncthreads();
        #pragma unroll
        for (int jj = 0; jj < 16; ++jj) {
            int n = p * 64 + dn * 16 + jj;
            t[w * 74 + dn * 16 + jj] = f2bf(x[(((size_t)(b * 256 + n) * 64) + hr) * 64 + w]);
        }
        __syncthreads();
        #pragma unroll
        for (int q = 0; q < 2; ++q) {
            int nl = q * 4 + dn;
            *(bf16x8*)(xT8 + XI(hp, p * 8 + nl, w + 1)) = *(const bf16x8*)(t + w * 74 + nl * 8);
        }
    }
    #undef XI
}

// ---------------- branch kernel: en (= e^{-2c}) and ekT (= e^{-2d}) ----------------
// A operands read directly from xT8 (coalesced 4x256B runs). LDS only for yc/ydl/ent:
// yc [64][72] bf16 9216 | ydl [64][67] f32 17152 | ent [64][264] bf16 33792 = 60160 B
// -> 2 blocks/CU, 4 waves/SIMD.
#define BR_YD_OFF  9216
#define BR_ENT_OFF (BR_YD_OFF + 17152)
#define BR_TOTAL   (BR_ENT_OFF + 33792)   // 60160

__global__ __launch_bounds__(512, 4) void k_branch(const short* __restrict__ xT8,
        const float* __restrict__ b_c1, const float* __restrict__ b_c2,
        const float* __restrict__ b_d1, const float* __restrict__ w_d2, const float* __restrict__ b_d2,
        const short* __restrict__ wc1f, const short* __restrict__ wc2f, const short* __restrict__ wd1f,
        short* __restrict__ en, float* __restrict__ ekT) {
    extern __shared__ char smem[];
    short* yc  = (short*)smem;
    float* ydl = (float*)(smem + BR_YD_OFF);
    short* ent = (short*)(smem + BR_ENT_OFF);

    const int rw = blockIdx.x;        // 512 blocks, 64 px (one row) each
    const int b = rw >> 6, h = rw & 63;
    const int p0 = rw << 6;
    const int tid = threadIdx.x;
    const int lane = tid & 63, wave = tid >> 6;
    const int l16 = lane & 15, lg = lane >> 4;
    const int wn = wave & 3, wm = wave >> 2;   // 2 (M) x 4 (N)
    const int cm = wn * 16 + l16;
    const size_t b66h = (size_t)(b * 66 + h);
    const int wcol = wm * 32 + l16;

    // A-fragment address for conv step KC (mt via +128)
    #define CONV_A(DST, KC) {                                                           \
        int k9_ = (KC) >> 3;                                                            \
        int kh_ = (k9_ * 11) >> 5, kw_ = k9_ - 3 * kh_;                                 \
        const short* xa_ = xT8 + (((b66h + kh_) * 32 + ((KC) & 7) * 4 + lg) * 66        \
                                  + wcol + kw_) * 8;                                    \
        DST[0] = *(const bf16x8*)(xa_);                                                 \
        DST[1] = *(const bf16x8*)(xa_ + 128);                                           \
    }

    // ---- GEMM1: yc[64px][64cm] = relu(x . w_c1^T + b_c1)
    {
        f32x4 acc[2] = {};
        const short* wp_ = wc1f + wn * 512 + lane * 8;
        const short* xg1 = xT8 + (((b66h + 1) * 32 + lg) * 66 + wcol + 1) * 8;  // + s*2112
        bf16x8 bcur = *(const bf16x8*)(wp_);
        bf16x8 a0 = *(const bf16x8*)(xg1), a1 = *(const bf16x8*)(xg1 + 128);
        #pragma unroll
        for (int s = 0; s < 8; ++s) {
            bf16x8 bc = bcur, c0 = a0, c1 = a1;
            if (s < 7) {
                bcur = *(const bf16x8*)(wp_ + (s + 1) * 2048);
                a0 = *(const bf16x8*)(xg1 + (s + 1) * 2112);
                a1 = *(const bf16x8*)(xg1 + (s + 1) * 2112 + 128);
            }
            acc[0] = __builtin_amdgcn_mfma_f32_16x16x32_bf16(c0, bc, acc[0], 0, 0, 0);
            acc[1] = __builtin_amdgcn_mfma_f32_16x16x32_bf16(c1, bc, acc[1], 0, 0, 0);
        }
        float bias = b_c1[cm];
        #pragma unroll
        for (int mt = 0; mt < 2; ++mt)
            #pragma unroll
            for (int r = 0; r < 4; ++r) {
                int px = wm * 32 + mt * 16 + lg * 4 + r;
                float v = acc[mt][r] + bias;
                yc[px * 72 + cm] = f2bf(v > 0.f ? v : 0.f);
            }
    }

    // ---- conv GEMM: yd[64px][64cm] = relu(conv3x3 + b_d1); depth-3 prefetch, 3-way unroll
    {
        f32x4 acc[2] = {};
        const short* wp_ = wd1f + wn * 512 + lane * 8;   // kc stride 2048
        bf16x8 b0 = *(const bf16x8*)(wp_);
        bf16x8 b1 = *(const bf16x8*)(wp_ + 2048);
        bf16x8 b2 = *(const bf16x8*)(wp_ + 4096);
        bf16x8 aA[2], aB[2], aC[2];
        CONV_A(aA, 0) CONV_A(aB, 1) CONV_A(aC, 2)
        for (int kc = 0; kc < 72; kc += 3) {
            {
                bf16x8 c0 = aA[0], c1 = aA[1], bc = b0;
                int cn = (kc + 3 < 72) ? kc + 3 : 71;
                CONV_A(aA, cn)
                b0 = *(const bf16x8*)(wp_ + cn * 2048);
                acc[0] = __builtin_amdgcn_mfma_f32_16x16x32_bf16(c0, bc, acc[0], 0, 0, 0);
                acc[1] = __builtin_amdgcn_mfma_f32_16x16x32_bf16(c1, bc, acc[1], 0, 0, 0);
            }
            {
                bf16x8 c0 = aB[0], c1 = aB[1], bc = b1;
                int cn = (kc + 4 < 72) ? kc + 4 : 71;
                CONV_A(aB, cn)
                b1 = *(const bf16x8*)(wp_ + cn * 2048);
                acc[0] = __builtin_amdgcn_mfma_f32_16x16x32_bf16(c0, bc, acc[0], 0, 0, 0);
                acc[1] = __builtin_amdgcn_mfma_f32_16x16x32_bf16(c1, bc, acc[1], 0, 0, 0);
            }
            {
                bf16x8 c0 = aC[0], c1 = aC[1], bc = b2;
                int cn = (kc + 5 < 72) ? kc + 5 : 71;
                CONV_A(aC, cn)
                b2 = *(const bf16x8*)(wp_ + cn * 2048);
                acc[0] = __builtin_amdgcn_mfma_f32_16x16x32_bf16(c0, bc, acc[0], 0, 0, 0);
                acc[1] = __builtin_amdgcn_mfma_f32_16x16x32_bf16(c1, bc, acc[1], 0, 0, 0);
            }
        }
        float bias = b_d1[cm];
        #pragma unroll
        for (int mt = 0; mt < 2; ++mt)
            #pragma unroll
            for (int r = 0; r < 4; ++r) {
                int px = wm * 32 + mt * 16 + lg * 4 + r;
                float v = acc[mt][r] + bias;
                ydl[px * 67 + cm] = v > 0.f ? v : 0.f;
            }
    }
    #undef CONV_A
    __syncthreads();   // yc + ydl ready

    // ---- GEMM2: c[64px][256] = yc . w_c2^T + b_c2 ; ent = exp(-2c)
    {
        f32x4 acc[2][4] = {};
        #pragma unroll
        for (int s = 0; s < 2; ++s) {
            int k0 = s * 32;
            bf16x8 afr[2], bfr[4];
            #pragma unroll
            for (int mt = 0; mt < 2; ++mt)
                afr[mt] = *(const bf16x8*)(yc + (wm * 32 + mt * 16 + l16) * 72 + k0 + lg * 8);
            #pragma unroll
            for (int nt = 0; nt < 4; ++nt)
                bfr[nt] = *(const bf16x8*)(wc2f + s * 8192 + (wn * 4 + nt) * 512 + lane * 8);
            #pragma unroll
            for (int mt = 0; mt < 2; ++mt)
                #pragma unroll
                for (int nt = 0; nt < 4; ++nt)
                    acc[mt][nt] = __builtin_amdgcn_mfma_f32_16x16x32_bf16(afr[mt], bfr[nt], acc[mt][nt], 0, 0, 0);
        }
        #pragma unroll
        for (int nt = 0; nt < 4; ++nt) {
            int nc = wn * 64 + nt * 16 + l16;
            float bias = b_c2[nc];
            #pragma unroll
            for (int mt = 0; mt < 2; ++mt)
                #pragma unroll
                for (int r = 0; r < 4; ++r) {
                    int px = wm * 32 + mt * 16 + lg * 4 + r;
                    float cv = acc[mt][nt][r] + bias;
                    ent[px * 264 + nc] = f2bf(exp2f(NEXP2 * cv));
                }
        }
    }

    // ---- d[px][9] = yd . w_d2^T + b_d2 ; ekT[k][p] = exp(-2d)  (px-minor, coalesced)
    for (int t = tid; t < 576; t += 512) {
        int k = t >> 6, px = t & 63;
        float sum = b_d2[k];
        const float* yr = ydl + px * 67;
        const float* wr = w_d2 + k * 64;
        #pragma unroll 8
        for (int m = 0; m < 64; ++m) sum += yr[m] * wr[m];
        ekT[(size_t)k * PTOT + p0 + px] = exp2f(NEXP2 * sum);
    }
    __syncthreads();   // ent ready

    // ---- coalesced en store
    for (int i = tid; i < 2048; i += 512) {
        int row = i >> 5, seg = i & 31;
        *(bf16x8*)(en + (size_t)(p0 + row) * 256 + seg * 8) = *(const bf16x8*)(ent + row * 264 + seg * 8);
    }
}

// ---------------- final kernel: out = (patches*attn) . W ----------------
// 256 blocks x 128 px (2 rows), 8 waves, fully-unrolled 9 phases; per phase:
//   load B0/B1 || zbuild(k+1) consuming xp + refilling xp with x(k+2) || GEMM(k) || barrier
// Single xp[8] (consume-and-refill) + launch_bounds(512,2): no register spills.
#define FN_ZSTR  268
#define FN_Z1    68608
#define FN_EKL   137216
#define FN_TOTAL 141824

__global__ __launch_bounds__(512, 2) void k_final(const short* __restrict__ xT8,
        const short* __restrict__ Wf, const short* __restrict__ en, const float* __restrict__ ekT,
        float* __restrict__ out) {
    extern __shared__ char smem[];
    short* z0  = (short*)smem;
    short* z1  = (short*)(smem + FN_Z1);
    float* ekl = (float*)(smem + FN_EKL);
    float* ot  = (float*)smem;   // epilogue reuse: [256][132] f32 = 135168 <= 141824

    const int rw = blockIdx.x;            // 256 blocks
    const int b = rw >> 5, h = (rw & 31) * 2;
    const int p0 = rw << 7;               // 128 px per block
    const int tid = threadIdx.x;
    const int lane = tid & 63, wave = tid >> 6;
    const int l16 = lane & 15, lg = lane >> 4;
    const int wn = wave & 3, wm = wave >> 2;   // GEMM: 2 (M, 64px) x 4 (N, 64o)

    for (int i = tid; i < 1152; i += 512)
        ekl[i] = ekT[(size_t)(i >> 7) * PTOT + p0 + (i & 127)];

    const int lpx = wave * 16 + l16;          // zbuild pixel
    const int r2 = lpx >> 6, ww = lpx & 63;
    // zbuild x address: (((b*66 + h+r2 + kh)*32 + j*4 + lg)*66 + ww + kw)*8
    const short* xbase = xT8 + (((size_t)(b * 66 + h + r2) * 32 + lg) * 66 + ww) * 8;

    bf16x8 e_regs[8];
    {
        const short* ep = en + (size_t)(p0 + lpx) * 256 + lg * 8;
        #pragma unroll
        for (int j = 0; j < 8; ++j) e_regs[j] = *(const bf16x8*)(ep + j * 32);
    }

    bf16x8 xp[8];
    #pragma unroll
    for (int j = 0; j < 8; ++j) xp[j] = *(const bf16x8*)(xbase + j * 2112);   // x(k=0)

    __syncthreads();               // ekl ready

    // ZBUILD(ZBUF, KK): consume xp (data for KK), refill xp with x(KK+1) (clamped)
    #define ZBUILD(ZBUF, KK) {                                                          \
        const int kk1 = ((KK) < 8) ? (KK) + 1 : 8;                                      \
        const int kh1 = (kk1 * 11) >> 5, kw1 = kk1 - 3 * kh1;                           \
        const short* xr_ = xbase + kh1 * 16896 + kw1 * 8;                               \
        float ekv = ekl[(KK) * 128 + lpx];                                              \
        short* zw_ = (ZBUF) + lpx * FN_ZSTR + lg * 8;                                   \
        _Pragma("unroll")                                                               \
        for (int j = 0; j < 8; ++j) {                                                   \
            bf16x8 x8 = xp[j];                                                          \
            xp[j] = *(const bf16x8*)(xr_ + j * 2112);                                   \
            bf16x8 e8 = e_regs[j];                                                      \
            i32x4 zz;                                                                   \
            _Pragma("unroll")                                                           \
            for (int i = 0; i < 4; ++i) {                                               \
                float q0 = __builtin_fmaf(ekv, bf2f(e8[2 * i]),     1.0f);              \
                float q1 = __builtin_fmaf(ekv, bf2f(e8[2 * i + 1]), 1.0f);              \
                zz[i] = cvt_pk_bf16(bf2f(x8[2 * i])     * __builtin_amdgcn_rcpf(q0),    \
                                    bf2f(x8[2 * i + 1]) * __builtin_amdgcn_rcpf(q1));   \
            }                                                                           \
            *(i32x4*)(zw_ + j * 32) = zz;                                               \
        }                                                                               \
    }

    ZBUILD(z0, 0)                  // z_0 ; xp <- x(1)
    __syncthreads();               // z0 ready

    // B fragment bases: fragment (kt = K*8+NC, ot = wn*4+nt) at Wf + kt*8192 + ot*512 + lane*8
    const short* wpB[4];
    #pragma unroll
    for (int nt = 0; nt < 4; ++nt) wpB[nt] = Wf + (wn * 4 + nt) * 512 + lane * 8;

    f32x4 acc[4][4] = {};
    const int abase = (wm * 64 + l16) * FN_ZSTR + lg * 8;

    #define GCHUNK(NC, BC, BP, DOPREF) {                                                \
        if (DOPREF) {                                                                   \
            _Pragma("unroll")                                                           \
            for (int nt = 0; nt < 4; ++nt)                                              \
                BP[nt] = *(const bf16x8*)(wpB[nt] + kbf + ((NC) + 2) * 8192);           \
        }                                                                               \
        bf16x8 afr[4];                                                                  \
        _Pragma("unroll")                                                               \
        for (int mt = 0; mt < 4; ++mt)                                                  \
            afr[mt] = *(const bf16x8*)(zR + abase + mt * 16 * FN_ZSTR + (NC) * 32);     \
        __builtin_amdgcn_s_setprio(1);                                                  \
        _Pragma("unroll")                                                               \
        for (int mt = 0; mt < 4; ++mt)                                                  \
            _Pragma("unroll")                                                           \
            for (int nt = 0; nt < 4; ++nt)                                              \
                acc[mt][nt] = __builtin_amdgcn_mfma_f32_16x16x32_bf16(afr[mt], BC[nt], acc[mt][nt], 0, 0, 0); \
        __builtin_amdgcn_s_setprio(0);                                                  \
    }
    #define PHASE(K, ZRB, ZWB) {                                                        \
        const short* zR = ZRB;                                                          \
        const int kbf = (K) * 65536;                                                    \
        bf16x8 B0[4], B1[4], B2[4];                                                     \
        _Pragma("unroll")                                                               \
        for (int nt = 0; nt < 4; ++nt) {                                                \
            B0[nt] = *(const bf16x8*)(wpB[nt] + kbf);                                   \
            B1[nt] = *(const bf16x8*)(wpB[nt] + kbf + 8192);                            \
        }                                                                               \
        if ((K) < 8) ZBUILD(ZWB, (K) + 1)                                               \
        GCHUNK(0, B0, B2, 1) GCHUNK(1, B1, B0, 1) GCHUNK(2, B2, B1, 1)                  \
        GCHUNK(3, B0, B2, 1) GCHUNK(4, B1, B0, 1) GCHUNK(5, B2, B1, 1)                  \
        GCHUNK(6, B0, B2, 0) GCHUNK(7, B1, B0, 0)                                       \
        __syncthreads();                                                                \
    }

    PHASE(0, z0, z1) PHASE(1, z1, z0) PHASE(2, z0, z1) PHASE(3, z1, z0)
    PHASE(4, z0, z1) PHASE(5, z1, z0) PHASE(6, z0, z1) PHASE(7, z1, z0)
    PHASE(8, z0, z1)

    #undef PHASE
    #undef GCHUNK
    #undef ZBUILD

    // epilogue: acc -> ot[o][132 px] f32, then coalesced stores
    #pragma unroll
    for (int nt = 0; nt < 4; ++nt) {
        int o = wn * 64 + nt * 16 + l16;
        #pragma unroll
        for (int mt = 0; mt < 4; ++mt) {
            int px = wm * 64 + mt * 16 + lg * 4;
            *(f32x4*)(ot + o * 132 + px) = acc[mt][nt];
        }
    }
    __syncthreads();
    {
        int o = tid >> 1, half = tid & 1;
        float* dst = out + (((size_t)b * 256 + o) * 64 + h + half) * 64;
        const float* srcp = ot + o * 132 + half * 64;
        #pragma unroll
        for (int j = 0; j < 16; ++j)
            *(f32x4*)(dst + 4 * j) = *(const f32x4*)(srcp + 4 * j);
    }
}

// ---------------- launcher ----------------
extern "C" void kernel_launch(void* const* d_in, const int* in_sizes, int n_in,
                              void* d_out, int out_size, void* d_ws, size_t ws_size,
                              hipStream_t stream) {
    const float* x    = (const float*)d_in[0];
    const float* w_c1 = (const float*)d_in[1];
    const float* b_c1 = (const float*)d_in[2];
    const float* w_c2 = (const float*)d_in[3];
    const float* b_c2 = (const float*)d_in[4];
    const float* w_d1 = (const float*)d_in[5];
    const float* b_d1 = (const float*)d_in[6];
    const float* w_d2 = (const float*)d_in[7];
    const float* b_d2 = (const float*)d_in[8];
    const float* Wt   = (const float*)d_in[9];
    float* out = (float*)d_out;
    char* ws = (char*)d_ws;

    short* wc1f = (short*)(ws + WS_WC1F);
    short* wc2f = (short*)(ws + WS_WC2F);
    short* wd1f = (short*)(ws + WS_WD1F);
    short* Wf   = (short*)(ws + WS_WF);
    float* ekT  = (float*)(ws + WS_EKT);
    short* en   = (short*)(ws + WS_EN);
    short* xT8  = (short*)(ws + WS_XT);

    (void)hipFuncSetAttribute((const void*)k_branch, hipFuncAttributeMaxDynamicSharedMemorySize, BR_TOTAL);
    (void)hipFuncSetAttribute((const void*)k_final,  hipFuncAttributeMaxDynamicSharedMemorySize, FN_TOTAL);

    k_prep<<<3008, 256, 0, stream>>>(Wt, w_d1, w_c1, w_c2, Wf, wd1f, wc1f, wc2f);
    k_prep_xt<<<512, 256, 0, stream>>>(x, xT8);
    k_branch<<<512, 512, BR_TOTAL, stream>>>(xT8, b_c1, b_c2, b_d1, w_d2, b_d2, wc1f, wc2f, wd1f, en, ekT);
    k_final<<<256, 512, FN_TOTAL, stream>>>(xT8, Wf, en, ekT, out);
}